// Round 1
// baseline (6238.089 us; speedup 1.0000x reference)
//
#include <hip/hip_runtime.h>
#include <hip/hip_cooperative_groups.h>

namespace cg = cooperative_groups;

// Shapes: B=8, T=96, N=2000, Dt=4, L=32, E=32. Nodes = N + T = 2096.

// ---------------- Kernel 1: spatial MLP -> X[:, 0:2000, :] ----------------
// Xs[b,n,:] = elu(cat(x[b,:,n], sp_emb[n,:]) @ sp_W1 + b1) @ sp_W2 + b2
__global__ __launch_bounds__(256) void k_spatial(
    const float* __restrict__ x, const float* __restrict__ sp_emb,
    const float* __restrict__ W1, const float* __restrict__ b1,
    const float* __restrict__ W2, const float* __restrict__ b2,
    float* __restrict__ X) {
  __shared__ float W1s[128 * 32];
  __shared__ float W2s[32 * 32];
  __shared__ float b1s[32], b2s[32];
  int tid = threadIdx.x;
  for (int i = tid; i < 128 * 32; i += 256) W1s[i] = W1[i];
  for (int i = tid; i < 32 * 32; i += 256) W2s[i] = W2[i];
  if (tid < 32) { b1s[tid] = b1[tid]; b2s[tid] = b2[tid]; }
  __syncthreads();
  int gidx = blockIdx.x * 256 + tid;
  if (gidx >= 8 * 2000) return;
  int b = gidx / 2000, n = gidx % 2000;
  float h1[32];
#pragma unroll
  for (int l = 0; l < 32; l++) h1[l] = b1s[l];
  for (int k = 0; k < 96; k++) {
    float xv = x[((size_t)b * 96 + k) * 2000 + n];
#pragma unroll
    for (int l = 0; l < 32; l++) h1[l] = fmaf(xv, W1s[k * 32 + l], h1[l]);
  }
  for (int e4 = 0; e4 < 8; e4++) {
    float4 ev = *reinterpret_cast<const float4*>(&sp_emb[(size_t)n * 32 + e4 * 4]);
    float evs[4] = {ev.x, ev.y, ev.z, ev.w};
#pragma unroll
    for (int q = 0; q < 4; q++) {
      int e = e4 * 4 + q;
#pragma unroll
      for (int l = 0; l < 32; l++) h1[l] = fmaf(evs[q], W1s[(96 + e) * 32 + l], h1[l]);
    }
  }
  float out[32];
#pragma unroll
  for (int j = 0; j < 32; j++) out[j] = b2s[j];
  for (int l = 0; l < 32; l++) {
    float a = h1[l] > 0.0f ? h1[l] : (__expf(h1[l]) - 1.0f);
#pragma unroll
    for (int j = 0; j < 32; j++) out[j] = fmaf(a, W2s[l * 32 + j], out[j]);
  }
  float* dst = X + ((size_t)b * 2096 + n) * 32;
#pragma unroll
  for (int j = 0; j < 32; j++) dst[j] = out[j];
}

// ---------------- Kernel 2: temporal GRU input gates precompute ----------------
// gi[b,t,g] = bih[g] + cat(x[b,t,:], x_mark[b,t,:], t_emb[t,:]) . Wih[g,:]
__global__ __launch_bounds__(256) void k_tgi(
    const float* __restrict__ x, const float* __restrict__ x_mark,
    const float* __restrict__ t_emb, const float* __restrict__ Wih,
    const float* __restrict__ bih, float* __restrict__ gi) {
  __shared__ float xs[8][2036];
  int tid = threadIdx.x;
  int row0 = blockIdx.x * 8;
  for (int rr = 0; rr < 8; rr++) {
    int row = row0 + rr;
    int b = row / 96, t = row % 96;
    for (int k = tid; k < 2036; k += 256) {
      float v;
      if (k < 2000) v = x[((size_t)b * 96 + t) * 2000 + k];
      else if (k < 2004) v = x_mark[((size_t)b * 96 + t) * 4 + (k - 2000)];
      else v = t_emb[(size_t)t * 32 + (k - 2004)];
      xs[rr][k] = v;
    }
  }
  __syncthreads();
  for (int oi = tid; oi < 8 * 96; oi += 256) {
    int rr = oi / 96, g = oi % 96;
    const float* w = Wih + (size_t)g * 2036;
    float acc = bih[g];
    for (int k = 0; k < 2036; k += 4) {
      float4 wv = *reinterpret_cast<const float4*>(w + k);
      acc = fmaf(xs[rr][k + 0], wv.x, acc);
      acc = fmaf(xs[rr][k + 1], wv.y, acc);
      acc = fmaf(xs[rr][k + 2], wv.z, acc);
      acc = fmaf(xs[rr][k + 3], wv.w, acc);
    }
    gi[(size_t)(row0 + rr) * 96 + g] = acc;
  }
}

// ---------------- Kernel 3: temporal GRU scan (hidden=32) -> X[:, 2000:2096, :] ----------------
__global__ __launch_bounds__(256) void k_tgru(
    const float* __restrict__ gi, const float* __restrict__ Whh,
    const float* __restrict__ bhh, float* __restrict__ X) {
  __shared__ float Whs[96][33];
  __shared__ float hs[8][33];
  int tid = threadIdx.x;
  for (int i = tid; i < 96 * 32; i += 256) Whs[i / 32][i % 32] = Whh[i];
  int b = tid >> 5, j = tid & 31;
  hs[b][j] = 0.0f;
  __syncthreads();
  for (int t = 0; t < 96; t++) {
    float gr = bhh[j], gz = bhh[32 + j], gn = bhh[64 + j];
#pragma unroll 8
    for (int k = 0; k < 32; k++) {
      float hv = hs[b][k];
      gr = fmaf(hv, Whs[j][k], gr);
      gz = fmaf(hv, Whs[32 + j][k], gz);
      gn = fmaf(hv, Whs[64 + j][k], gn);
    }
    const float* g = gi + ((size_t)b * 96 + t) * 96;
    float ir = g[j], iz = g[32 + j], inn = g[64 + j];
    float r = 1.0f / (1.0f + __expf(-(ir + gr)));
    float z = 1.0f / (1.0f + __expf(-(iz + gz)));
    float n = tanhf(inn + r * gn);
    float hn = (1.0f - z) * n + z * hs[b][j];
    __syncthreads();
    hs[b][j] = hn;
    X[((size_t)b * 2096 + 2000 + t) * 32 + j] = hn;
    __syncthreads();
  }
}

// ---------------- Kernel 4: fused GNN pass ----------------
// Xout = elu( (A @ Xin) @ W + bias ), A = tanh(relu(Xa @ Xa^T)), A recomputed on the fly.
__global__ __launch_bounds__(256) void k_gnn(
    const float* __restrict__ Xa, const float* __restrict__ Xin,
    float* __restrict__ Xout, const float* __restrict__ W,
    const float* __restrict__ bias) {
  __shared__ float XaR[32][36];
  __shared__ float Xm[64][36];
  __shared__ float Xi[64][36];
  __shared__ float At[32][68];
  __shared__ float Ws[32][36];
  __shared__ float bs[32];
  int tid = threadIdx.x;
  int b = blockIdx.y;
  int r0 = blockIdx.x * 32;
  const float* Xab = Xa + (size_t)b * 2096 * 32;
  const float* Xib = Xin + (size_t)b * 2096 * 32;
  for (int i = tid; i < 32 * 32; i += 256) {
    int r = i >> 5, k = i & 31;
    XaR[r][k] = (r0 + r < 2096) ? Xab[(size_t)(r0 + r) * 32 + k] : 0.0f;
    Ws[r][k] = W[i];
  }
  if (tid < 32) bs[tid] = bias[tid];
  float acc[4] = {0.f, 0.f, 0.f, 0.f};
  int sm = tid & 63, rq = tid >> 6;  // S-phase mapping
  int ar = tid & 31, fg = tid >> 5;  // acc-phase mapping
  for (int mt = 0; mt < 33; mt++) {
    int m0 = mt * 64;
    __syncthreads();
    for (int i = tid; i < 64 * 32; i += 256) {
      int m = i >> 5, k = i & 31;
      int gm = m0 + m;
      bool ok = gm < 2096;
      Xm[m][k] = ok ? Xab[(size_t)gm * 32 + k] : 0.0f;
      Xi[m][k] = ok ? Xib[(size_t)gm * 32 + k] : 0.0f;
    }
    __syncthreads();
    // S phase: thread computes S[rq*8 + i][sm], i<8; A = tanh(relu(S))
    float xm[32];
#pragma unroll
    for (int k4 = 0; k4 < 8; k4++) {
      float4 v = *reinterpret_cast<const float4*>(&Xm[sm][k4 * 4]);
      xm[k4 * 4 + 0] = v.x; xm[k4 * 4 + 1] = v.y;
      xm[k4 * 4 + 2] = v.z; xm[k4 * 4 + 3] = v.w;
    }
#pragma unroll
    for (int i = 0; i < 8; i++) {
      int r = rq * 8 + i;
      float s = 0.0f;
#pragma unroll
      for (int k4 = 0; k4 < 8; k4++) {
        float4 xa = *reinterpret_cast<const float4*>(&XaR[r][k4 * 4]);
        s = fmaf(xa.x, xm[k4 * 4 + 0], s);
        s = fmaf(xa.y, xm[k4 * 4 + 1], s);
        s = fmaf(xa.z, xm[k4 * 4 + 2], s);
        s = fmaf(xa.w, xm[k4 * 4 + 3], s);
      }
      // tanh(relu(s)) branchless: s<=0 -> e=1 -> 0
      float e = __expf(-2.0f * fmaxf(s, 0.0f));
      At[r][sm] = (1.0f - e) / (1.0f + e);
    }
    __syncthreads();
    // acc phase: acc[r][fg*4..+3] += sum_m A[r][m] * Xi[m][f]
    int f0 = fg * 4;
#pragma unroll
    for (int m = 0; m < 64; m += 4) {
      float4 av = *reinterpret_cast<const float4*>(&At[ar][m]);
      float4 x0 = *reinterpret_cast<const float4*>(&Xi[m + 0][f0]);
      float4 x1 = *reinterpret_cast<const float4*>(&Xi[m + 1][f0]);
      float4 x2 = *reinterpret_cast<const float4*>(&Xi[m + 2][f0]);
      float4 x3 = *reinterpret_cast<const float4*>(&Xi[m + 3][f0]);
      acc[0] = fmaf(av.x, x0.x, acc[0]); acc[1] = fmaf(av.x, x0.y, acc[1]);
      acc[2] = fmaf(av.x, x0.z, acc[2]); acc[3] = fmaf(av.x, x0.w, acc[3]);
      acc[0] = fmaf(av.y, x1.x, acc[0]); acc[1] = fmaf(av.y, x1.y, acc[1]);
      acc[2] = fmaf(av.y, x1.z, acc[2]); acc[3] = fmaf(av.y, x1.w, acc[3]);
      acc[0] = fmaf(av.z, x2.x, acc[0]); acc[1] = fmaf(av.z, x2.y, acc[1]);
      acc[2] = fmaf(av.z, x2.z, acc[2]); acc[3] = fmaf(av.z, x2.w, acc[3]);
      acc[0] = fmaf(av.w, x3.x, acc[0]); acc[1] = fmaf(av.w, x3.y, acc[1]);
      acc[2] = fmaf(av.w, x3.z, acc[2]); acc[3] = fmaf(av.w, x3.w, acc[3]);
    }
  }
  // epilogue: stage M = A@Xin into Xm rows 0..31, then out = elu(M @ W + b)
  __syncthreads();
  {
    int f0 = fg * 4;
    Xm[ar][f0 + 0] = acc[0]; Xm[ar][f0 + 1] = acc[1];
    Xm[ar][f0 + 2] = acc[2]; Xm[ar][f0 + 3] = acc[3];
  }
  __syncthreads();
  int f0 = fg * 4;
  float o[4];
#pragma unroll
  for (int j = 0; j < 4; j++) o[j] = bs[f0 + j];
#pragma unroll
  for (int k = 0; k < 32; k++) {
    float mv = Xm[ar][k];
    float4 wv = *reinterpret_cast<const float4*>(&Ws[k][f0]);
    o[0] = fmaf(mv, wv.x, o[0]);
    o[1] = fmaf(mv, wv.y, o[1]);
    o[2] = fmaf(mv, wv.z, o[2]);
    o[3] = fmaf(mv, wv.w, o[3]);
  }
  int grr = r0 + ar;
  if (grr < 2096) {
    float* dst = Xout + ((size_t)b * 2096 + grr) * 32 + f0;
#pragma unroll
    for (int j = 0; j < 4; j++) {
      float v = o[j];
      dst[j] = v > 0.0f ? v : (__expf(v) - 1.0f);
    }
  }
}

// ---------------- Kernel 5: spatial readout MLP rs ----------------
// rs[b,n,:] = elu(X[b,n,:32] @ fr_W1 + fr_b1) @ fr_W2 + fr_b2
__global__ __launch_bounds__(256) void k_rs(
    const float* __restrict__ X, const float* __restrict__ W1,
    const float* __restrict__ b1, const float* __restrict__ W2,
    const float* __restrict__ b2, float* __restrict__ rs) {
  __shared__ float Xt[32][33];
  __shared__ float W2s[96][100];
  __shared__ float Hl[32][100];
  __shared__ float b1s[96], b2s[96];
  int tid = threadIdx.x;
  int b = blockIdx.y;
  int n0 = blockIdx.x * 32;
  for (int i = tid; i < 96 * 96; i += 256) W2s[i / 96][i % 96] = W2[i];
  if (tid < 96) { b1s[tid] = b1[tid]; b2s[tid] = b2[tid]; }
  for (int i = tid; i < 32 * 32; i += 256) {
    int r = i >> 5, k = i & 31;
    Xt[r][k] = (n0 + r < 2000) ? X[((size_t)b * 2096 + n0 + r) * 32 + k] : 0.0f;
  }
  __syncthreads();
  int r = tid & 31, cg = tid >> 5;  // cg<8, 12 cols each
#pragma unroll
  for (int i = 0; i < 12; i++) {
    int c = cg * 12 + i;
    float a = b1s[c];
    for (int k = 0; k < 32; k++) a = fmaf(Xt[r][k], W1[k * 96 + c], a);
    Hl[r][c] = a > 0.0f ? a : (__expf(a) - 1.0f);
  }
  __syncthreads();
  float o[12];
#pragma unroll
  for (int i = 0; i < 12; i++) o[i] = b2s[cg * 12 + i];
  for (int k = 0; k < 96; k++) {
    float hv = Hl[r][k];
#pragma unroll
    for (int i = 0; i < 12; i++) o[i] = fmaf(hv, W2s[k][cg * 12 + i], o[i]);
  }
  if (n0 + r < 2000) {
    float* dst = rs + ((size_t)b * 2000 + n0 + r) * 96 + cg * 12;
#pragma unroll
    for (int i = 0; i < 12; i++) dst[i] = o[i];
  }
}

// ---------------- Kernel 6: tr-GRU input gates precompute ----------------
// gi[b,t,g] = bih[g] + X[b, 2000+t, :32] . Wih[g,:32]   (g < 6000)
__global__ __launch_bounds__(256) void k_trgi(
    const float* __restrict__ X, const float* __restrict__ Wih,
    const float* __restrict__ bih, float* __restrict__ gi) {
  __shared__ float Xs[96][33];
  __shared__ float Wsh[384][33];
  int tid = threadIdx.x;
  int b = blockIdx.y;
  int g0 = blockIdx.x * 384;
  for (int i = tid; i < 96 * 32; i += 256) {
    int t = i >> 5, k = i & 31;
    Xs[t][k] = X[((size_t)b * 2096 + 2000 + t) * 32 + k];
  }
  for (int i = tid; i < 384 * 32; i += 256) {
    int g = i >> 5, k = i & 31;
    Wsh[g][k] = (g0 + g < 6000) ? Wih[(size_t)(g0 + g) * 32 + k] : 0.0f;
  }
  __syncthreads();
  for (int oi = tid; oi < 96 * 384; oi += 256) {
    int t = oi / 384, g = oi % 384;
    if (g0 + g >= 6000) continue;
    float a = bih[g0 + g];
#pragma unroll
    for (int k = 0; k < 32; k++) a = fmaf(Xs[t][k], Wsh[g][k], a);
    gi[((size_t)b * 96 + t) * 6000 + g0 + g] = a;
  }
}

// ---------------- Kernel 7: tr-GRU scan (hidden=2000), cooperative ----------------
__global__ __launch_bounds__(256) void k_trgru(
    const float* __restrict__ gi, const float* __restrict__ Whh,
    const float* __restrict__ bhh, float* h0, float* h1,
    float* __restrict__ rt) {
  cg::grid_group grid = cg::this_grid();
  int tid = threadIdx.x;
  int ks = tid >> 6;            // k-slice 0..3
  int j = (tid >> 3) & 7;       // local hidden idx 0..7
  int b = tid & 7;              // batch 0..7
  int jg = blockIdx.x * 8 + j;  // global hidden idx 0..1999
  __shared__ float part[3][8][8][4];
  // zero initial hidden state
  for (int i = blockIdx.x * 256 + tid; i < 16000; i += gridDim.x * 256) h0[i] = 0.0f;
  grid.sync();
  float* hp = h0;
  float* hn = h1;
  const float* wr = Whh + (size_t)jg * 2000;
  const float* wz = Whh + (size_t)(2000 + jg) * 2000;
  const float* wn = Whh + (size_t)(4000 + jg) * 2000;
  int k0 = ks * 500;
  for (int t = 0; t < 96; t++) {
    float ar = 0.f, az = 0.f, an = 0.f;
    const float* hb = hp + (size_t)b * 2000;
    for (int k = k0; k < k0 + 500; k += 4) {
      float4 hv = *reinterpret_cast<const float4*>(hb + k);
      float4 wv = *reinterpret_cast<const float4*>(wr + k);
      ar = fmaf(hv.x, wv.x, ar); ar = fmaf(hv.y, wv.y, ar);
      ar = fmaf(hv.z, wv.z, ar); ar = fmaf(hv.w, wv.w, ar);
      wv = *reinterpret_cast<const float4*>(wz + k);
      az = fmaf(hv.x, wv.x, az); az = fmaf(hv.y, wv.y, az);
      az = fmaf(hv.z, wv.z, az); az = fmaf(hv.w, wv.w, az);
      wv = *reinterpret_cast<const float4*>(wn + k);
      an = fmaf(hv.x, wv.x, an); an = fmaf(hv.y, wv.y, an);
      an = fmaf(hv.z, wv.z, an); an = fmaf(hv.w, wv.w, an);
    }
    part[0][j][b][ks] = ar;
    part[1][j][b][ks] = az;
    part[2][j][b][ks] = an;
    __syncthreads();
    if (ks == 0) {
      float gr = part[0][j][b][0] + part[0][j][b][1] + part[0][j][b][2] + part[0][j][b][3] + bhh[jg];
      float gz = part[1][j][b][0] + part[1][j][b][1] + part[1][j][b][2] + part[1][j][b][3] + bhh[2000 + jg];
      float gn = part[2][j][b][0] + part[2][j][b][1] + part[2][j][b][2] + part[2][j][b][3] + bhh[4000 + jg];
      const float* g = gi + ((size_t)b * 96 + t) * 6000;
      float r = 1.0f / (1.0f + __expf(-(g[jg] + gr)));
      float z = 1.0f / (1.0f + __expf(-(g[2000 + jg] + gz)));
      float n = tanhf(g[4000 + jg] + r * gn);
      float hnew = (1.0f - z) * n + z * hb[jg];
      hn[(size_t)b * 2000 + jg] = hnew;
      rt[((size_t)b * 96 + t) * 2000 + jg] = hnew;
    }
    grid.sync();
    float* tmp = hp; hp = hn; hn = tmp;
  }
}

// ---------------- Kernel 8: final combine + out matmul ----------------
// out[b,n] = out_b + sum_t (rs[b,n,t] + rt[b,t,n]) * out_W[t]
__global__ __launch_bounds__(256) void k_final(
    const float* __restrict__ rs, const float* __restrict__ rt,
    const float* __restrict__ outW, const float* __restrict__ outb,
    float* __restrict__ out) {
  __shared__ float w[96];
  __shared__ float ob;
  int tid = threadIdx.x;
  if (tid < 96) w[tid] = outW[tid];
  if (tid == 0) ob = outb[0];
  __syncthreads();
  int gidx = blockIdx.x * 256 + tid;
  if (gidx >= 16000) return;
  int b = gidx / 2000, n = gidx % 2000;
  const float* rsp = rs + (size_t)gidx * 96;
  float acc = ob;
  for (int t4 = 0; t4 < 24; t4++) {
    float4 rv = *reinterpret_cast<const float4*>(rsp + t4 * 4);
    int t = t4 * 4;
    acc = fmaf(rv.x + rt[((size_t)b * 96 + t + 0) * 2000 + n], w[t + 0], acc);
    acc = fmaf(rv.y + rt[((size_t)b * 96 + t + 1) * 2000 + n], w[t + 1], acc);
    acc = fmaf(rv.z + rt[((size_t)b * 96 + t + 2) * 2000 + n], w[t + 2], acc);
    acc = fmaf(rv.w + rt[((size_t)b * 96 + t + 3) * 2000 + n], w[t + 3], acc);
  }
  out[gidx] = acc;
}

extern "C" void kernel_launch(void* const* d_in, const int* in_sizes, int n_in,
                              void* d_out, int out_size, void* d_ws, size_t ws_size,
                              hipStream_t stream) {
  const float* x      = (const float*)d_in[0];
  const float* x_mark = (const float*)d_in[1];
  const float* sp_emb = (const float*)d_in[2];
  const float* sp_W1  = (const float*)d_in[3];
  const float* sp_b1  = (const float*)d_in[4];
  const float* sp_W2  = (const float*)d_in[5];
  const float* sp_b2  = (const float*)d_in[6];
  const float* t_emb  = (const float*)d_in[7];
  const float* t_Wih  = (const float*)d_in[8];
  const float* t_Whh  = (const float*)d_in[9];
  const float* t_bih  = (const float*)d_in[10];
  const float* t_bhh  = (const float*)d_in[11];
  const float* gcn_W  = (const float*)d_in[12];
  const float* gcn_b  = (const float*)d_in[13];
  const float* fr_W1  = (const float*)d_in[14];
  const float* fr_b1  = (const float*)d_in[15];
  const float* fr_W2  = (const float*)d_in[16];
  const float* fr_b2  = (const float*)d_in[17];
  const float* tr_Wih = (const float*)d_in[18];
  const float* tr_Whh = (const float*)d_in[19];
  const float* tr_bih = (const float*)d_in[20];
  const float* tr_bhh = (const float*)d_in[21];
  const float* out_W  = (const float*)d_in[22];
  const float* out_b  = (const float*)d_in[23];
  (void)in_sizes; (void)n_in; (void)out_size; (void)ws_size;

  float* ws = (float*)d_ws;
  float* X0   = ws;                    // 8*2096*32 = 536576
  float* X1   = X0 + 536576;
  float* X2   = X1 + 536576;
  float* tgi  = X2 + 536576;           // 768*96 = 73728
  float* trgi = tgi + 73728;           // 8*96*6000 = 4608000
  float* h0   = trgi + 4608000;        // 16000
  float* h1   = h0 + 16000;            // 16000
  float* rt   = h1 + 16000;            // 8*96*2000 = 1536000
  float* rs   = rt + 1536000;          // 8*2000*96 = 1536000

  k_spatial<<<63, 256, 0, stream>>>(x, sp_emb, sp_W1, sp_b1, sp_W2, sp_b2, X0);
  k_tgi<<<96, 256, 0, stream>>>(x, x_mark, t_emb, t_Wih, t_bih, tgi);
  k_tgru<<<1, 256, 0, stream>>>(tgi, t_Whh, t_bhh, X0);

  dim3 gg(66, 8);
  // TN layer 0: A from X0
  k_gnn<<<gg, 256, 0, stream>>>(X0, X0, X1, gcn_W + 0 * 1024, gcn_b + 0 * 32);
  k_gnn<<<gg, 256, 0, stream>>>(X0, X1, X2, gcn_W + 1 * 1024, gcn_b + 1 * 32);
  // TN layer 1: A from X2
  k_gnn<<<gg, 256, 0, stream>>>(X2, X2, X0, gcn_W + 2 * 1024, gcn_b + 2 * 32);
  k_gnn<<<gg, 256, 0, stream>>>(X2, X0, X1, gcn_W + 3 * 1024, gcn_b + 3 * 32);

  k_rs<<<dim3(63, 8), 256, 0, stream>>>(X1, fr_W1, fr_b1, fr_W2, fr_b2, rs);
  k_trgi<<<dim3(16, 8), 256, 0, stream>>>(X1, tr_Wih, tr_bih, trgi);

  {
    const float* a0 = trgi;
    const float* a1 = tr_Whh;
    const float* a2 = tr_bhh;
    float* a3 = h0;
    float* a4 = h1;
    float* a5 = rt;
    void* cargs[] = {&a0, &a1, &a2, &a3, &a4, &a5};
    hipLaunchCooperativeKernel((const void*)k_trgru, dim3(250), dim3(256), cargs, 0, stream);
  }

  k_final<<<63, 256, 0, stream>>>(rs, rt, out_W, out_b, (float*)d_out);
}

// Round 2
// 2837.044 us; speedup vs baseline: 2.1988x; 2.1988x over previous
//
#include <hip/hip_runtime.h>

typedef _Float16 h2 __attribute__((ext_vector_type(2)));
typedef _Float16 h4 __attribute__((ext_vector_type(4)));
typedef _Float16 h8 __attribute__((ext_vector_type(8)));

#define NBLK 250

__device__ inline float dot8(h8 w, h8 v, float acc) {
#if __has_builtin(__builtin_amdgcn_fdot2)
  acc = __builtin_amdgcn_fdot2(__builtin_shufflevector(w, w, 0, 1),
                               __builtin_shufflevector(v, v, 0, 1), acc, false);
  acc = __builtin_amdgcn_fdot2(__builtin_shufflevector(w, w, 2, 3),
                               __builtin_shufflevector(v, v, 2, 3), acc, false);
  acc = __builtin_amdgcn_fdot2(__builtin_shufflevector(w, w, 4, 5),
                               __builtin_shufflevector(v, v, 4, 5), acc, false);
  acc = __builtin_amdgcn_fdot2(__builtin_shufflevector(w, w, 6, 7),
                               __builtin_shufflevector(v, v, 6, 7), acc, false);
#else
#pragma unroll
  for (int j = 0; j < 8; j++) acc = fmaf((float)w[j], (float)v[j], acc);
#endif
  return acc;
}

// ---------------- Kernel 1: spatial MLP -> X[:, 0:2000, :] ----------------
__global__ __launch_bounds__(256) void k_spatial(
    const float* __restrict__ x, const float* __restrict__ sp_emb,
    const float* __restrict__ W1, const float* __restrict__ b1,
    const float* __restrict__ W2, const float* __restrict__ b2,
    float* __restrict__ X) {
  __shared__ float W1s[128 * 32];
  __shared__ float W2s[32 * 32];
  __shared__ float b1s[32], b2s[32];
  int tid = threadIdx.x;
  for (int i = tid; i < 128 * 32; i += 256) W1s[i] = W1[i];
  for (int i = tid; i < 32 * 32; i += 256) W2s[i] = W2[i];
  if (tid < 32) { b1s[tid] = b1[tid]; b2s[tid] = b2[tid]; }
  __syncthreads();
  int gidx = blockIdx.x * 256 + tid;
  if (gidx >= 8 * 2000) return;
  int b = gidx / 2000, n = gidx % 2000;
  float h1[32];
#pragma unroll
  for (int l = 0; l < 32; l++) h1[l] = b1s[l];
  for (int k = 0; k < 96; k++) {
    float xv = x[((size_t)b * 96 + k) * 2000 + n];
#pragma unroll
    for (int l = 0; l < 32; l++) h1[l] = fmaf(xv, W1s[k * 32 + l], h1[l]);
  }
  for (int e4 = 0; e4 < 8; e4++) {
    float4 ev = *reinterpret_cast<const float4*>(&sp_emb[(size_t)n * 32 + e4 * 4]);
    float evs[4] = {ev.x, ev.y, ev.z, ev.w};
#pragma unroll
    for (int q = 0; q < 4; q++) {
      int e = e4 * 4 + q;
#pragma unroll
      for (int l = 0; l < 32; l++) h1[l] = fmaf(evs[q], W1s[(96 + e) * 32 + l], h1[l]);
    }
  }
  float out[32];
#pragma unroll
  for (int j = 0; j < 32; j++) out[j] = b2s[j];
  for (int l = 0; l < 32; l++) {
    float a = h1[l] > 0.0f ? h1[l] : (__expf(h1[l]) - 1.0f);
#pragma unroll
    for (int j = 0; j < 32; j++) out[j] = fmaf(a, W2s[l * 32 + j], out[j]);
  }
  float* dst = X + ((size_t)b * 2096 + n) * 32;
#pragma unroll
  for (int j = 0; j < 32; j++) dst[j] = out[j];
}

// ---------------- Kernel 2: temporal GRU input gates precompute ----------------
__global__ __launch_bounds__(256) void k_tgi(
    const float* __restrict__ x, const float* __restrict__ x_mark,
    const float* __restrict__ t_emb, const float* __restrict__ Wih,
    const float* __restrict__ bih, float* __restrict__ gi) {
  __shared__ float xs[8][2036];
  int tid = threadIdx.x;
  int row0 = blockIdx.x * 8;
  for (int rr = 0; rr < 8; rr++) {
    int row = row0 + rr;
    int b = row / 96, t = row % 96;
    for (int k = tid; k < 2036; k += 256) {
      float v;
      if (k < 2000) v = x[((size_t)b * 96 + t) * 2000 + k];
      else if (k < 2004) v = x_mark[((size_t)b * 96 + t) * 4 + (k - 2000)];
      else v = t_emb[(size_t)t * 32 + (k - 2004)];
      xs[rr][k] = v;
    }
  }
  __syncthreads();
  for (int oi = tid; oi < 8 * 96; oi += 256) {
    int rr = oi / 96, g = oi % 96;
    const float* w = Wih + (size_t)g * 2036;
    float acc = bih[g];
    for (int k = 0; k < 2036; k += 4) {
      float4 wv = *reinterpret_cast<const float4*>(w + k);
      acc = fmaf(xs[rr][k + 0], wv.x, acc);
      acc = fmaf(xs[rr][k + 1], wv.y, acc);
      acc = fmaf(xs[rr][k + 2], wv.z, acc);
      acc = fmaf(xs[rr][k + 3], wv.w, acc);
    }
    gi[(size_t)(row0 + rr) * 96 + g] = acc;
  }
}

// ---------------- Kernel 3: temporal GRU scan (hidden=32) ----------------
__global__ __launch_bounds__(256) void k_tgru(
    const float* __restrict__ gi, const float* __restrict__ Whh,
    const float* __restrict__ bhh, float* __restrict__ X) {
  __shared__ float Whs[96][33];
  __shared__ float hs[8][33];
  int tid = threadIdx.x;
  for (int i = tid; i < 96 * 32; i += 256) Whs[i / 32][i % 32] = Whh[i];
  int b = tid >> 5, j = tid & 31;
  hs[b][j] = 0.0f;
  __syncthreads();
  for (int t = 0; t < 96; t++) {
    float gr = bhh[j], gz = bhh[32 + j], gn = bhh[64 + j];
#pragma unroll 8
    for (int k = 0; k < 32; k++) {
      float hv = hs[b][k];
      gr = fmaf(hv, Whs[j][k], gr);
      gz = fmaf(hv, Whs[32 + j][k], gz);
      gn = fmaf(hv, Whs[64 + j][k], gn);
    }
    const float* g = gi + ((size_t)b * 96 + t) * 96;
    float ir = g[j], iz = g[32 + j], inn = g[64 + j];
    float r = 1.0f / (1.0f + __expf(-(ir + gr)));
    float z = 1.0f / (1.0f + __expf(-(iz + gz)));
    float n = tanhf(inn + r * gn);
    float hn = (1.0f - z) * n + z * hs[b][j];
    __syncthreads();
    hs[b][j] = hn;
    X[((size_t)b * 2096 + 2000 + t) * 32 + j] = hn;
    __syncthreads();
  }
}

// ---------------- Kernel 4: fused GNN pass ----------------
__global__ __launch_bounds__(256) void k_gnn(
    const float* __restrict__ Xa, const float* __restrict__ Xin,
    float* __restrict__ Xout, const float* __restrict__ W,
    const float* __restrict__ bias) {
  __shared__ float XaR[32][36];
  __shared__ float Xm[64][36];
  __shared__ float Xi[64][36];
  __shared__ float At[32][68];
  __shared__ float Ws[32][36];
  __shared__ float bs[32];
  int tid = threadIdx.x;
  int b = blockIdx.y;
  int r0 = blockIdx.x * 32;
  const float* Xab = Xa + (size_t)b * 2096 * 32;
  const float* Xib = Xin + (size_t)b * 2096 * 32;
  for (int i = tid; i < 32 * 32; i += 256) {
    int r = i >> 5, k = i & 31;
    XaR[r][k] = (r0 + r < 2096) ? Xab[(size_t)(r0 + r) * 32 + k] : 0.0f;
    Ws[r][k] = W[i];
  }
  if (tid < 32) bs[tid] = bias[tid];
  float acc[4] = {0.f, 0.f, 0.f, 0.f};
  int sm = tid & 63, rq = tid >> 6;
  int ar = tid & 31, fg = tid >> 5;
  for (int mt = 0; mt < 33; mt++) {
    int m0 = mt * 64;
    __syncthreads();
    for (int i = tid; i < 64 * 32; i += 256) {
      int m = i >> 5, k = i & 31;
      int gm = m0 + m;
      bool ok = gm < 2096;
      Xm[m][k] = ok ? Xab[(size_t)gm * 32 + k] : 0.0f;
      Xi[m][k] = ok ? Xib[(size_t)gm * 32 + k] : 0.0f;
    }
    __syncthreads();
    float xm[32];
#pragma unroll
    for (int k4 = 0; k4 < 8; k4++) {
      float4 v = *reinterpret_cast<const float4*>(&Xm[sm][k4 * 4]);
      xm[k4 * 4 + 0] = v.x; xm[k4 * 4 + 1] = v.y;
      xm[k4 * 4 + 2] = v.z; xm[k4 * 4 + 3] = v.w;
    }
#pragma unroll
    for (int i = 0; i < 8; i++) {
      int r = rq * 8 + i;
      float s = 0.0f;
#pragma unroll
      for (int k4 = 0; k4 < 8; k4++) {
        float4 xa = *reinterpret_cast<const float4*>(&XaR[r][k4 * 4]);
        s = fmaf(xa.x, xm[k4 * 4 + 0], s);
        s = fmaf(xa.y, xm[k4 * 4 + 1], s);
        s = fmaf(xa.z, xm[k4 * 4 + 2], s);
        s = fmaf(xa.w, xm[k4 * 4 + 3], s);
      }
      float e = __expf(-2.0f * fmaxf(s, 0.0f));
      At[r][sm] = (1.0f - e) / (1.0f + e);
    }
    __syncthreads();
    int f0 = fg * 4;
#pragma unroll
    for (int m = 0; m < 64; m += 4) {
      float4 av = *reinterpret_cast<const float4*>(&At[ar][m]);
      float4 x0 = *reinterpret_cast<const float4*>(&Xi[m + 0][f0]);
      float4 x1 = *reinterpret_cast<const float4*>(&Xi[m + 1][f0]);
      float4 x2 = *reinterpret_cast<const float4*>(&Xi[m + 2][f0]);
      float4 x3 = *reinterpret_cast<const float4*>(&Xi[m + 3][f0]);
      acc[0] = fmaf(av.x, x0.x, acc[0]); acc[1] = fmaf(av.x, x0.y, acc[1]);
      acc[2] = fmaf(av.x, x0.z, acc[2]); acc[3] = fmaf(av.x, x0.w, acc[3]);
      acc[0] = fmaf(av.y, x1.x, acc[0]); acc[1] = fmaf(av.y, x1.y, acc[1]);
      acc[2] = fmaf(av.y, x1.z, acc[2]); acc[3] = fmaf(av.y, x1.w, acc[3]);
      acc[0] = fmaf(av.z, x2.x, acc[0]); acc[1] = fmaf(av.z, x2.y, acc[1]);
      acc[2] = fmaf(av.z, x2.z, acc[2]); acc[3] = fmaf(av.z, x2.w, acc[3]);
      acc[0] = fmaf(av.w, x3.x, acc[0]); acc[1] = fmaf(av.w, x3.y, acc[1]);
      acc[2] = fmaf(av.w, x3.z, acc[2]); acc[3] = fmaf(av.w, x3.w, acc[3]);
    }
  }
  __syncthreads();
  {
    int f0 = fg * 4;
    Xm[ar][f0 + 0] = acc[0]; Xm[ar][f0 + 1] = acc[1];
    Xm[ar][f0 + 2] = acc[2]; Xm[ar][f0 + 3] = acc[3];
  }
  __syncthreads();
  int f0 = fg * 4;
  float o[4];
#pragma unroll
  for (int j = 0; j < 4; j++) o[j] = bs[f0 + j];
#pragma unroll
  for (int k = 0; k < 32; k++) {
    float mv = Xm[ar][k];
    float4 wv = *reinterpret_cast<const float4*>(&Ws[k][f0]);
    o[0] = fmaf(mv, wv.x, o[0]);
    o[1] = fmaf(mv, wv.y, o[1]);
    o[2] = fmaf(mv, wv.z, o[2]);
    o[3] = fmaf(mv, wv.w, o[3]);
  }
  int grr = r0 + ar;
  if (grr < 2096) {
    float* dst = Xout + ((size_t)b * 2096 + grr) * 32 + f0;
#pragma unroll
    for (int j = 0; j < 4; j++) {
      float v = o[j];
      dst[j] = v > 0.0f ? v : (__expf(v) - 1.0f);
    }
  }
}

// ---------------- Kernel 5: spatial readout MLP rs ----------------
__global__ __launch_bounds__(256) void k_rs(
    const float* __restrict__ X, const float* __restrict__ W1,
    const float* __restrict__ b1, const float* __restrict__ W2,
    const float* __restrict__ b2, float* __restrict__ rs) {
  __shared__ float Xt[32][33];
  __shared__ float W2s[96][100];
  __shared__ float Hl[32][100];
  __shared__ float b1s[96], b2s[96];
  int tid = threadIdx.x;
  int b = blockIdx.y;
  int n0 = blockIdx.x * 32;
  for (int i = tid; i < 96 * 96; i += 256) W2s[i / 96][i % 96] = W2[i];
  if (tid < 96) { b1s[tid] = b1[tid]; b2s[tid] = b2[tid]; }
  for (int i = tid; i < 32 * 32; i += 256) {
    int r = i >> 5, k = i & 31;
    Xt[r][k] = (n0 + r < 2000) ? X[((size_t)b * 2096 + n0 + r) * 32 + k] : 0.0f;
  }
  __syncthreads();
  int r = tid & 31, cg = tid >> 5;
#pragma unroll
  for (int i = 0; i < 12; i++) {
    int c = cg * 12 + i;
    float a = b1s[c];
    for (int k = 0; k < 32; k++) a = fmaf(Xt[r][k], W1[k * 96 + c], a);
    Hl[r][c] = a > 0.0f ? a : (__expf(a) - 1.0f);
  }
  __syncthreads();
  float o[12];
#pragma unroll
  for (int i = 0; i < 12; i++) o[i] = b2s[cg * 12 + i];
  for (int k = 0; k < 96; k++) {
    float hv = Hl[r][k];
#pragma unroll
    for (int i = 0; i < 12; i++) o[i] = fmaf(hv, W2s[k][cg * 12 + i], o[i]);
  }
  if (n0 + r < 2000) {
    float* dst = rs + ((size_t)b * 2000 + n0 + r) * 96 + cg * 12;
#pragma unroll
    for (int i = 0; i < 12; i++) dst[i] = o[i];
  }
}

// ---------------- Kernel 6: tr-GRU input gates precompute ----------------
__global__ __launch_bounds__(256) void k_trgi(
    const float* __restrict__ X, const float* __restrict__ Wih,
    const float* __restrict__ bih, float* __restrict__ gi) {
  __shared__ float Xs[96][33];
  __shared__ float Wsh[384][33];
  int tid = threadIdx.x;
  int b = blockIdx.y;
  int g0 = blockIdx.x * 384;
  for (int i = tid; i < 96 * 32; i += 256) {
    int t = i >> 5, k = i & 31;
    Xs[t][k] = X[((size_t)b * 2096 + 2000 + t) * 32 + k];
  }
  for (int i = tid; i < 384 * 32; i += 256) {
    int g = i >> 5, k = i & 31;
    Wsh[g][k] = (g0 + g < 6000) ? Wih[(size_t)(g0 + g) * 32 + k] : 0.0f;
  }
  __syncthreads();
  for (int oi = tid; oi < 96 * 384; oi += 256) {
    int t = oi / 384, g = oi % 384;
    if (g0 + g >= 6000) continue;
    float a = bih[g0 + g];
#pragma unroll
    for (int k = 0; k < 32; k++) a = fmaf(Xs[t][k], Wsh[g][k], a);
    gi[((size_t)b * 96 + t) * 6000 + g0 + g] = a;
  }
}

// ---------------- Kernel 6b: init counters + zero h ----------------
__global__ __launch_bounds__(256) void k_init(int* __restrict__ cnt,
                                              _Float16* __restrict__ hA) {
  int i = blockIdx.x * 256 + threadIdx.x;
  if (i < 128) cnt[i] = 0;
  if (i < 16000) hA[i] = (_Float16)0.0f;
}

// ---------------- Kernel 7: tr-GRU scan (hidden=2000), persistent, LDS weights ----------------
__global__ __launch_bounds__(1024) void k_trgru(
    const float* __restrict__ gi, const float* __restrict__ whh,
    const float* __restrict__ bhh, _Float16* __restrict__ hA,
    _Float16* __restrict__ hB, float* __restrict__ rt,
    int* __restrict__ cnt) {
  __shared__ _Float16 wlds[24][2000];   // 24 rows: gate g*8 + lj -> Whh[g*2000 + blk*8 + lj]
  __shared__ _Float16 hlds[8][2008];    // padded: stride 1004 words -> conflict-free
  __shared__ float part[4][24][8];
  int tid = threadIdx.x;
  int blk = blockIdx.x;

  // one-time weight load + f32->f16 convert into LDS
  for (int i = tid; i < 12000; i += 1024) {
    int r = i / 500;
    int kc = (i % 500) * 4;
    int g = r >> 3, lj = r & 7;
    float4 v = *reinterpret_cast<const float4*>(
        whh + ((size_t)(g * 2000 + blk * 8 + lj)) * 2000 + kc);
    h4 o = {(_Float16)v.x, (_Float16)v.y, (_Float16)v.z, (_Float16)v.w};
    *reinterpret_cast<h4*>(&wlds[r][kc]) = o;
  }

  int ks = tid >> 8;         // 0..3  K-slice
  int r = (tid >> 3) & 31;   // 0..31 (active < 24): row = gate*8 + lj
  int b = tid & 7;
  bool active = (r < 24);
  int k0 = ks * 504;
  int k1 = (ks == 3) ? 2000 : (k0 + 504);  // 504,504,504,488 (all %8==0, tail 8 after 16-chunks)

  // gate-combine threads (tid<64) keep their h in f32 register
  int cj = tid >> 3, cb = tid & 7;
  int jg = blk * 8 + cj;
  float hold = 0.0f;
  float bR = 0.f, bZ = 0.f, bN = 0.f;
  if (tid < 64) {
    bR = bhh[jg]; bZ = bhh[2000 + jg]; bN = bhh[4000 + jg];
  }
  __syncthreads();

  for (int t = 0; t < 96; t++) {
    const _Float16* hc = (t & 1) ? hB : hA;
    _Float16* hn = (t & 1) ? hA : hB;
    // stage h_{t-1} (full, all batches) into LDS
    for (int i = tid; i < 2000; i += 1024) {
      int bb = i / 250;
      int kc = (i % 250) * 8;
      *reinterpret_cast<h8*>(&hlds[bb][kc]) =
          *reinterpret_cast<const h8*>(hc + bb * 2000 + kc);
    }
    __syncthreads();
    if (active) {
      const _Float16* wp = &wlds[r][0];
      const _Float16* hp = &hlds[b][0];
      float a0 = 0.f, a1 = 0.f;
      int k = k0;
      for (; k + 16 <= k1; k += 16) {
        a0 = dot8(*reinterpret_cast<const h8*>(wp + k),
                  *reinterpret_cast<const h8*>(hp + k), a0);
        a1 = dot8(*reinterpret_cast<const h8*>(wp + k + 8),
                  *reinterpret_cast<const h8*>(hp + k + 8), a1);
      }
      a0 = dot8(*reinterpret_cast<const h8*>(wp + k),
                *reinterpret_cast<const h8*>(hp + k), a0);  // tail 8
      part[ks][r][b] = a0 + a1;
    }
    __syncthreads();
    if (tid < 64) {
      float gr = part[0][cj][cb] + part[1][cj][cb] + part[2][cj][cb] + part[3][cj][cb] + bR;
      float gz = part[0][8 + cj][cb] + part[1][8 + cj][cb] + part[2][8 + cj][cb] + part[3][8 + cj][cb] + bZ;
      float gn = part[0][16 + cj][cb] + part[1][16 + cj][cb] + part[2][16 + cj][cb] + part[3][16 + cj][cb] + bN;
      const float* gp = gi + ((size_t)cb * 96 + t) * 6000;
      float rr = 1.0f / (1.0f + __expf(-(gp[jg] + gr)));
      float zz = 1.0f / (1.0f + __expf(-(gp[2000 + jg] + gz)));
      float nn = tanhf(gp[4000 + jg] + rr * gn);
      hold = (1.0f - zz) * nn + zz * hold;
      hn[cb * 2000 + jg] = (_Float16)hold;
      rt[((size_t)cb * 96 + t) * 2000 + jg] = hold;
    }
    __syncthreads();  // drains vmem writes before the release
    if (tid == 0) {
      __hip_atomic_fetch_add(&cnt[t + 1], 1, __ATOMIC_RELEASE, __HIP_MEMORY_SCOPE_AGENT);
      while (__hip_atomic_load(&cnt[t + 1], __ATOMIC_ACQUIRE, __HIP_MEMORY_SCOPE_AGENT) < NBLK) {
        __builtin_amdgcn_s_sleep(1);
      }
    }
    __syncthreads();
  }
}

// ---------------- Kernel 8: final combine + out matmul ----------------
__global__ __launch_bounds__(256) void k_final(
    const float* __restrict__ rs, const float* __restrict__ rt,
    const float* __restrict__ outW, const float* __restrict__ outb,
    float* __restrict__ out) {
  __shared__ float w[96];
  __shared__ float ob;
  int tid = threadIdx.x;
  if (tid < 96) w[tid] = outW[tid];
  if (tid == 0) ob = outb[0];
  __syncthreads();
  int gidx = blockIdx.x * 256 + tid;
  if (gidx >= 16000) return;
  int b = gidx / 2000, n = gidx % 2000;
  const float* rsp = rs + (size_t)gidx * 96;
  float acc = ob;
  for (int t4 = 0; t4 < 24; t4++) {
    float4 rv = *reinterpret_cast<const float4*>(rsp + t4 * 4);
    int t = t4 * 4;
    acc = fmaf(rv.x + rt[((size_t)b * 96 + t + 0) * 2000 + n], w[t + 0], acc);
    acc = fmaf(rv.y + rt[((size_t)b * 96 + t + 1) * 2000 + n], w[t + 1], acc);
    acc = fmaf(rv.z + rt[((size_t)b * 96 + t + 2) * 2000 + n], w[t + 2], acc);
    acc = fmaf(rv.w + rt[((size_t)b * 96 + t + 3) * 2000 + n], w[t + 3], acc);
  }
  out[gidx] = acc;
}

extern "C" void kernel_launch(void* const* d_in, const int* in_sizes, int n_in,
                              void* d_out, int out_size, void* d_ws, size_t ws_size,
                              hipStream_t stream) {
  const float* x      = (const float*)d_in[0];
  const float* x_mark = (const float*)d_in[1];
  const float* sp_emb = (const float*)d_in[2];
  const float* sp_W1  = (const float*)d_in[3];
  const float* sp_b1  = (const float*)d_in[4];
  const float* sp_W2  = (const float*)d_in[5];
  const float* sp_b2  = (const float*)d_in[6];
  const float* t_emb  = (const float*)d_in[7];
  const float* t_Wih  = (const float*)d_in[8];
  const float* t_Whh  = (const float*)d_in[9];
  const float* t_bih  = (const float*)d_in[10];
  const float* t_bhh  = (const float*)d_in[11];
  const float* gcn_W  = (const float*)d_in[12];
  const float* gcn_b  = (const float*)d_in[13];
  const float* fr_W1  = (const float*)d_in[14];
  const float* fr_b1  = (const float*)d_in[15];
  const float* fr_W2  = (const float*)d_in[16];
  const float* fr_b2  = (const float*)d_in[17];
  const float* tr_Wih = (const float*)d_in[18];
  const float* tr_Whh = (const float*)d_in[19];
  const float* tr_bih = (const float*)d_in[20];
  const float* tr_bhh = (const float*)d_in[21];
  const float* out_W  = (const float*)d_in[22];
  const float* out_b  = (const float*)d_in[23];
  (void)in_sizes; (void)n_in; (void)out_size; (void)ws_size;

  float* ws = (float*)d_ws;
  float* X0   = ws;                    // 8*2096*32 = 536576
  float* X1   = X0 + 536576;
  float* X2   = X1 + 536576;
  float* tgi  = X2 + 536576;           // 768*96 = 73728
  float* trgi = tgi + 73728;           // 8*96*6000 = 4608000
  float* hsl  = trgi + 4608000;        // 16000 f32 slot -> hA/hB (f16, 16000 each)
  float* cns  = hsl + 16000;           // 16000 f32 slot -> cnt
  float* rt   = cns + 16000;           // 8*96*2000 = 1536000
  float* rs   = rt + 1536000;          // 8*2000*96 = 1536000

  _Float16* hA = (_Float16*)hsl;
  _Float16* hB = hA + 16000;
  int* cnt = (int*)cns;

  k_init<<<63, 256, 0, stream>>>(cnt, hA);
  k_spatial<<<63, 256, 0, stream>>>(x, sp_emb, sp_W1, sp_b1, sp_W2, sp_b2, X0);
  k_tgi<<<96, 256, 0, stream>>>(x, x_mark, t_emb, t_Wih, t_bih, tgi);
  k_tgru<<<1, 256, 0, stream>>>(tgi, t_Whh, t_bhh, X0);

  dim3 gg(66, 8);
  k_gnn<<<gg, 256, 0, stream>>>(X0, X0, X1, gcn_W + 0 * 1024, gcn_b + 0 * 32);
  k_gnn<<<gg, 256, 0, stream>>>(X0, X1, X2, gcn_W + 1 * 1024, gcn_b + 1 * 32);
  k_gnn<<<gg, 256, 0, stream>>>(X2, X2, X0, gcn_W + 2 * 1024, gcn_b + 2 * 32);
  k_gnn<<<gg, 256, 0, stream>>>(X2, X0, X1, gcn_W + 3 * 1024, gcn_b + 3 * 32);

  k_rs<<<dim3(63, 8), 256, 0, stream>>>(X1, fr_W1, fr_b1, fr_W2, fr_b2, rs);
  k_trgi<<<dim3(16, 8), 256, 0, stream>>>(X1, tr_Wih, tr_bih, trgi);

  {
    const float* a0 = trgi;
    const float* a1 = tr_Whh;
    const float* a2 = tr_bhh;
    _Float16* a3 = hA;
    _Float16* a4 = hB;
    float* a5 = rt;
    int* a6 = cnt;
    void* cargs[] = {&a0, &a1, &a2, &a3, &a4, &a5, &a6};
    hipLaunchCooperativeKernel((const void*)k_trgru, dim3(250), dim3(1024), cargs, 0, stream);
  }

  k_final<<<63, 256, 0, stream>>>(rs, rt, out_W, out_b, (float*)d_out);
}